// Round 5
// baseline (142.642 us; speedup 1.0000x reference)
//
#include <hip/hip_runtime.h>

#define LSEQ 8192
#define E 1024
#define H 16
#define NSHARD 16

typedef __attribute__((ext_vector_type(8))) short short8;
typedef __attribute__((ext_vector_type(4))) float f32x4;

__device__ inline unsigned short f2bf(float f) {
    union { float f; unsigned int i; } v; v.f = f;
    unsigned int x = v.i;
    return (unsigned short)((x + 0x7fffu + ((x >> 16) & 1u)) >> 16);
}

__device__ inline float wave_reduce_sum(float v) {
    #pragma unroll
    for (int off = 32; off > 0; off >>= 1) v += __shfl_xor(v, off, 64);
    return v;
}

// kA: fused q + r + c, plus zero-init of atomic shard buffers.
// Block (h = beta&15, ec = beta>>4): same-h blocks land on one XCD (%8 round
// robin heuristic) so the 16x redundant Wq_h read is served by that XCD's L2.
//  phase 0: zero partial shards (4 KB/block) + S_shard (block 0)
//  phase 1: q_h[d] = Wq[h*64+d,:].x + bq   (wave w owns d = w*16..w*16+15)
//  phase 2: r_bf[h][e] = bf16(0.125 * sum_d q_h[d] Wk[h*64+d, e]), e=ec*64+lane
//           c[h] = 0.125 * q_h . bk_h      (ec==0 only)
__global__ __launch_bounds__(256) void kA_qrc(
    const float* __restrict__ x, const float* __restrict__ W,
    const float* __restrict__ b, unsigned short* __restrict__ r_bf,
    float* __restrict__ c_ws, float* __restrict__ partial,
    float* __restrict__ S_shard)
{
    __shared__ float q_lds[64];
    __shared__ float red[4][64];
    const int beta = blockIdx.x;
    const int h = beta & 15, ec = beta >> 4;
    const int tid = threadIdx.x;
    const int wave = tid >> 6, lane = tid & 63;

    // phase 0: zero shard buffers (stream-ordered before k2's atomics)
    {
        f32x4 z = {0.f, 0.f, 0.f, 0.f};
        ((f32x4*)partial)[beta * 256 + tid] = z;   // 256 blocks * 4 KB = 1 MB
        if (beta == 0) S_shard[tid] = 0.f;         // 256 floats
    }

    // phase 1: q_h (each wave: 16 full-row dots)
    {
        const f32x4* xp = (const f32x4*)(x) + lane * 4;
        f32x4 x0 = xp[0], x1 = xp[1], x2 = xp[2], x3 = xp[3];
        #pragma unroll 4
        for (int i = 0; i < 16; i++) {
            int d = wave * 16 + i;
            const f32x4* wp = (const f32x4*)(W + (h * 64 + d) * E) + lane * 4;
            f32x4 w0 = wp[0], w1 = wp[1], w2 = wp[2], w3 = wp[3];
            float s = w0[0]*x0[0] + w0[1]*x0[1] + w0[2]*x0[2] + w0[3]*x0[3]
                    + w1[0]*x1[0] + w1[1]*x1[1] + w1[2]*x1[2] + w1[3]*x1[3]
                    + w2[0]*x2[0] + w2[1]*x2[1] + w2[2]*x2[2] + w2[3]*x2[3]
                    + w3[0]*x3[0] + w3[1]*x3[1] + w3[2]*x3[2] + w3[3]*x3[3];
            s = wave_reduce_sum(s);
            if (lane == 0) q_lds[d] = s + b[h * 64 + d];
        }
    }
    __syncthreads();

    // phase 2: r (this block's 64-column slice) and c (ec==0)
    {
        int e = ec * 64 + lane;
        float acc = 0.f;
        #pragma unroll
        for (int i = 0; i < 16; i++) {
            int d = wave * 16 + i;
            acc += q_lds[d] * W[(E + h * 64 + d) * E + e];
        }
        red[wave][lane] = acc;
        __syncthreads();
        if (wave == 0) {
            float s = red[0][lane] + red[1][lane] + red[2][lane] + red[3][lane];
            r_bf[h * E + e] = f2bf(s * 0.125f);
        }
        if (ec == 0 && wave == 1) {
            float v = q_lds[lane] * b[E + h * 64 + lane];
            v = wave_reduce_sum(v);
            if (lane == 0) c_ws[h] = v * 0.125f;
        }
    }
}

// k2: single pass over x. Block beta owns rows [beta*32, beta*32+32):
//   scores via MFMA -> p = exp(score) (no max; scores ~ N(0,1))
//   -> register u-partials -> atomicAdd into shard (beta&15)
__global__ __launch_bounds__(512, 1) void k2_fused(
    const float* __restrict__ x,
    const unsigned short* __restrict__ r_bf,
    const float* __restrict__ c_ws,
    float* __restrict__ partial, float* __restrict__ S_shard)
{
    __shared__ float x_lds[16 * 1028];   // 16 rows, stride 1028 (pad 4)
    __shared__ float sp[8 * 64 * 4];     // per-wave MFMA partials
    __shared__ float p_lds[16 * 16];     // [row][head]
    __shared__ float esum[16];

    const int tid  = threadIdx.x;
    const int wave = tid >> 6, lane = tid & 63;
    const int beta = blockIdx.x;

    if (tid < 16) esum[tid] = 0.f;
    float acc[32];   // 16 heads x 2 cols (cols tid*2, tid*2+1)
    #pragma unroll
    for (int i = 0; i < 32; i++) acc[i] = 0.f;
    int lbase = beta * 32;

    for (int t = 0; t < 2; t++) {
        int R0 = lbase + t * 16;
        __syncthreads();
        // stage 16 fp32 rows into LDS (coalesced)
        {
            int row = tid >> 5, ch = tid & 31;
            const f32x4* src = (const f32x4*)(x + (R0 + row) * E);
            float* dst = x_lds + row * 1028;
            #pragma unroll
            for (int j = 0; j < 8; j++) {
                int c4 = ch + 32 * j;
                *(f32x4*)(dst + c4 * 4) = src[c4];
            }
        }
        __syncthreads();
        // MFMA: wave w covers K window [w*128, w*128+128)
        {
            int rw = lane & 15, quad = lane >> 4;
            f32x4 sacc = {0.f, 0.f, 0.f, 0.f};
            const float* arow = x_lds + rw * 1028 + wave * 128 + quad * 8;
            const short8* bp = (const short8*)(r_bf + rw * E + wave * 128 + quad * 8);
            #pragma unroll
            for (int kk = 0; kk < 4; kk++) {
                f32x4 a0 = *(const f32x4*)(arow + kk * 32);
                f32x4 a1 = *(const f32x4*)(arow + kk * 32 + 4);
                short8 af;
                af[0] = (short)f2bf(a0[0]); af[1] = (short)f2bf(a0[1]);
                af[2] = (short)f2bf(a0[2]); af[3] = (short)f2bf(a0[3]);
                af[4] = (short)f2bf(a1[0]); af[5] = (short)f2bf(a1[1]);
                af[6] = (short)f2bf(a1[2]); af[7] = (short)f2bf(a1[3]);
                short8 bfr = bp[kk * 4];
                sacc = __builtin_amdgcn_mfma_f32_16x16x32_bf16(af, bfr, sacc, 0, 0, 0);
            }
            *(f32x4*)&sp[(wave * 64 + lane) * 4] = sacc;
        }
        __syncthreads();
        // p = exp(score)  (C/D layout: col=lane&15, row=quad*4+reg)
        if (tid < 256) {
            int m = tid >> 4, hh = tid & 15;
            int ln = (m >> 2) * 16 + hh, rg = m & 3;
            float s = c_ws[hh];
            #pragma unroll
            for (int w = 0; w < 8; w++) s += sp[(w * 64 + ln) * 4 + rg];
            float p = __expf(s);
            p_lds[m * 16 + hh] = p;
            atomicAdd(&esum[hh], p);
        }
        __syncthreads();
        // accumulate u partial: thread owns 2 cols x 16 heads
        #pragma unroll 4
        for (int m = 0; m < 16; m++) {
            float2 xv = *(const float2*)&x_lds[m * 1028 + tid * 2];
            const f32x4* pp = (const f32x4*)&p_lds[m * 16];
            #pragma unroll
            for (int g = 0; g < 4; g++) {
                f32x4 pv = pp[g];
                acc[(g * 4 + 0) * 2 + 0] += pv[0] * xv.x;
                acc[(g * 4 + 0) * 2 + 1] += pv[0] * xv.y;
                acc[(g * 4 + 1) * 2 + 0] += pv[1] * xv.x;
                acc[(g * 4 + 1) * 2 + 1] += pv[1] * xv.y;
                acc[(g * 4 + 2) * 2 + 0] += pv[2] * xv.x;
                acc[(g * 4 + 2) * 2 + 1] += pv[2] * xv.y;
                acc[(g * 4 + 3) * 2 + 0] += pv[3] * xv.x;
                acc[(g * 4 + 3) * 2 + 1] += pv[3] * xv.y;
            }
        }
    }
    __syncthreads();
    // atomic accumulate into shard (beta & 15)
    {
        float* pb = partial + (beta & 15) * (H * E);
        #pragma unroll
        for (int h = 0; h < 16; h++) {
            atomicAdd(&pb[h * E + tid * 2],     acc[h * 2]);
            atomicAdd(&pb[h * E + tid * 2 + 1], acc[h * 2 + 1]);
        }
        if (tid < 16) atomicAdd(&S_shard[(beta & 15) * 16 + tid], esum[tid]);
    }
}

// k4: oh[i] = (Wv[i,:].u_h)/S_h + bv[i], with u_h = sum of 16 shards (to LDS).
__global__ __launch_bounds__(256) void k4_oh(
    const float* __restrict__ W, const float* __restrict__ bias,
    const float* __restrict__ partial, const float* __restrict__ S_shard,
    float* __restrict__ oh_ws)
{
    __shared__ float u_lds[1024];
    const int tid = threadIdx.x;
    const int wave = tid >> 6, lane = tid & 63;
    const int h = blockIdx.x >> 4;     // 4 outputs/block, 64 per head

    // shard-reduce u_h into LDS (coalesced dword reads, L2-resident)
    for (int e = tid; e < 1024; e += 256) {
        float s = 0.f;
        #pragma unroll
        for (int sh = 0; sh < NSHARD; sh++) s += partial[sh * (H * E) + h * E + e];
        u_lds[e] = s;
    }
    float Sh = 0.f;
    #pragma unroll
    for (int sh = 0; sh < NSHARD; sh++) Sh += S_shard[sh * 16 + h];
    __syncthreads();

    int i = blockIdx.x * 4 + wave;
    const f32x4* wp = (const f32x4*)(W + (2 * E + i) * E);
    const f32x4* up = (const f32x4*)u_lds;
    float s = 0.f;
    #pragma unroll
    for (int j = 0; j < 4; j++) {
        f32x4 w4 = wp[j * 64 + lane], u4 = up[j * 64 + lane];
        s += w4[0]*u4[0] + w4[1]*u4[1] + w4[2]*u4[2] + w4[3]*u4[3];
    }
    s = wave_reduce_sum(s);
    if (lane == 0) oh_ws[i] = s / Sh + bias[2 * E + i];
}

// k5: out[j] = Wout[j,:].oh + bout[j]. One wave per output.
__global__ __launch_bounds__(256) void k5_out(
    const float* __restrict__ Wout, const float* __restrict__ bout,
    const float* __restrict__ oh_ws, float* __restrict__ out)
{
    int wave = threadIdx.x >> 6, lane = threadIdx.x & 63;
    int j = blockIdx.x * 4 + wave;
    const f32x4* wp = (const f32x4*)(Wout + j * E) + lane * 4;
    const f32x4* op = (const f32x4*)(oh_ws) + lane * 4;
    float s = 0.f;
    #pragma unroll
    for (int jj = 0; jj < 4; jj++) {
        f32x4 w4 = wp[jj], o4 = op[jj];
        s += w4[0]*o4[0] + w4[1]*o4[1] + w4[2]*o4[2] + w4[3]*o4[3];
    }
    s = wave_reduce_sum(s);
    if (lane == 0) out[j] = s + bout[j];
}

extern "C" void kernel_launch(void* const* d_in, const int* in_sizes, int n_in,
                              void* d_out, int out_size, void* d_ws, size_t ws_size,
                              hipStream_t stream) {
    const float* x  = (const float*)d_in[0];
    const float* W  = (const float*)d_in[1];
    const float* b  = (const float*)d_in[2];
    const float* Wo = (const float*)d_in[3];
    const float* bo = (const float*)d_in[4];
    float* out = (float*)d_out;
    char* ws = (char*)d_ws;

    float* c_ws    = (float*)(ws);                  // 64 B
    float* S_shard = (float*)(ws + 1024);           // 1024 B (16 shards x 16 h)
    float* oh_ws   = (float*)(ws + 4096);           // 4096 B
    unsigned short* r_bf = (unsigned short*)(ws + 8192);  // 32768 B
    float* partial = (float*)(ws + 65536);          // 16 shards x 64 KB = 1 MB

    hipLaunchKernelGGL(kA_qrc,  dim3(256), dim3(256), 0, stream,
                       x, W, b, r_bf, c_ws, partial, S_shard);
    hipLaunchKernelGGL(k2_fused, dim3(256), dim3(512), 0, stream,
                       x, r_bf, c_ws, partial, S_shard);
    hipLaunchKernelGGL(k4_oh,   dim3(256), dim3(256), 0, stream,
                       W, b, partial, S_shard, oh_ws);
    hipLaunchKernelGGL(k5_out,  dim3(256), dim3(256), 0, stream,
                       Wo, bo, oh_ws, out);
}

// Round 6
// 125.043 us; speedup vs baseline: 1.1407x; 1.1407x over previous
//
#include <hip/hip_runtime.h>

#define LSEQ 8192
#define E 1024
#define H 16
#define NSHARD 16

typedef __attribute__((ext_vector_type(8))) short short8;
typedef __attribute__((ext_vector_type(4))) float f32x4;

__device__ inline float bf2f(unsigned int u16) {
    union { unsigned int i; float f; } v;
    v.i = (u16 & 0xffffu) << 16;
    return v.f;
}

__device__ inline unsigned short f2bf(float f) {
    union { float f; unsigned int i; } v; v.f = f;
    unsigned int x = v.i;
    return (unsigned short)((x + 0x7fffu + ((x >> 16) & 1u)) >> 16);
}

__device__ inline float wave_reduce_sum(float v) {
    #pragma unroll
    for (int off = 32; off > 0; off >>= 1) v += __shfl_xor(v, off, 64);
    return v;
}

// kA: fused q + r + c + S_shard zero-init.
// Block (h = beta&15, ec = beta>>4): same-h blocks share Wq_h reads via L2/L3.
__global__ __launch_bounds__(256) void kA_qrc(
    const float* __restrict__ x, const float* __restrict__ W,
    const float* __restrict__ b, unsigned short* __restrict__ r_bf,
    float* __restrict__ c_ws, float* __restrict__ S_shard)
{
    __shared__ float q_lds[64];
    __shared__ float red[4][64];
    const int beta = blockIdx.x;
    const int h = beta & 15, ec = beta >> 4;
    const int tid = threadIdx.x;
    const int wave = tid >> 6, lane = tid & 63;

    if (beta == 0) S_shard[tid] = 0.f;   // 256 = NSHARD*16 floats

    // phase 1: q_h[d] = Wq[h*64+d,:].x + bq  (wave w owns d = w*16..w*16+15)
    {
        const f32x4* xp = (const f32x4*)(x) + lane * 4;
        f32x4 x0 = xp[0], x1 = xp[1], x2 = xp[2], x3 = xp[3];
        #pragma unroll 4
        for (int i = 0; i < 16; i++) {
            int d = wave * 16 + i;
            const f32x4* wp = (const f32x4*)(W + (h * 64 + d) * E) + lane * 4;
            f32x4 w0 = wp[0], w1 = wp[1], w2 = wp[2], w3 = wp[3];
            float s = w0[0]*x0[0] + w0[1]*x0[1] + w0[2]*x0[2] + w0[3]*x0[3]
                    + w1[0]*x1[0] + w1[1]*x1[1] + w1[2]*x1[2] + w1[3]*x1[3]
                    + w2[0]*x2[0] + w2[1]*x2[1] + w2[2]*x2[2] + w2[3]*x2[3]
                    + w3[0]*x3[0] + w3[1]*x3[1] + w3[2]*x3[2] + w3[3]*x3[3];
            s = wave_reduce_sum(s);
            if (lane == 0) q_lds[d] = s + b[h * 64 + d];
        }
    }
    __syncthreads();

    // phase 2: r_bf[h][e] (e = ec*64+lane) and c (ec==0)
    {
        int e = ec * 64 + lane;
        float acc = 0.f;
        #pragma unroll
        for (int i = 0; i < 16; i++) {
            int d = wave * 16 + i;
            acc += q_lds[d] * W[(E + h * 64 + d) * E + e];
        }
        red[wave][lane] = acc;
        __syncthreads();
        if (wave == 0) {
            float s = red[0][lane] + red[1][lane] + red[2][lane] + red[3][lane];
            r_bf[h * E + e] = f2bf(s * 0.125f);
        }
        if (ec == 0 && wave == 1) {
            float v = q_lds[lane] * b[E + h * 64 + lane];
            v = wave_reduce_sum(v);
            if (lane == 0) c_ws[h] = v * 0.125f;
        }
    }
}

// k2: single pass over x. Block beta owns rows [beta*32, beta*32+32):
//   scores via MFMA -> p = exp(score) (no max; scores ~ N(0,1))
//   -> register u-partials -> PLAIN store as packed bf16 (no atomics)
//   -> S_shard[beta&15] += esum (low-contention atomics)
__global__ __launch_bounds__(512, 1) void k2_fused(
    const float* __restrict__ x,
    const unsigned short* __restrict__ r_bf,
    const float* __restrict__ c_ws,
    unsigned int* __restrict__ partial_bf, float* __restrict__ S_shard)
{
    __shared__ float x_lds[16 * 1028];   // 16 rows, stride 1028 (pad 4)
    __shared__ float sp[8 * 64 * 4];     // per-wave MFMA partials
    __shared__ float p_lds[16 * 16];     // [row][head]
    __shared__ float esum[16];

    const int tid  = threadIdx.x;
    const int wave = tid >> 6, lane = tid & 63;
    const int beta = blockIdx.x;

    if (tid < 16) esum[tid] = 0.f;
    float acc[32];   // 16 heads x 2 cols (cols tid*2, tid*2+1)
    #pragma unroll
    for (int i = 0; i < 32; i++) acc[i] = 0.f;
    int lbase = beta * 32;

    for (int t = 0; t < 2; t++) {
        int R0 = lbase + t * 16;
        __syncthreads();
        // stage 16 fp32 rows into LDS (coalesced)
        {
            int row = tid >> 5, ch = tid & 31;
            const f32x4* src = (const f32x4*)(x + (R0 + row) * E);
            float* dst = x_lds + row * 1028;
            #pragma unroll
            for (int j = 0; j < 8; j++) {
                int c4 = ch + 32 * j;
                *(f32x4*)(dst + c4 * 4) = src[c4];
            }
        }
        __syncthreads();
        // MFMA: wave w covers K window [w*128, w*128+128)
        {
            int rw = lane & 15, quad = lane >> 4;
            f32x4 sacc = {0.f, 0.f, 0.f, 0.f};
            const float* arow = x_lds + rw * 1028 + wave * 128 + quad * 8;
            const short8* bp = (const short8*)(r_bf + rw * E + wave * 128 + quad * 8);
            #pragma unroll
            for (int kk = 0; kk < 4; kk++) {
                f32x4 a0 = *(const f32x4*)(arow + kk * 32);
                f32x4 a1 = *(const f32x4*)(arow + kk * 32 + 4);
                short8 af;
                af[0] = (short)f2bf(a0[0]); af[1] = (short)f2bf(a0[1]);
                af[2] = (short)f2bf(a0[2]); af[3] = (short)f2bf(a0[3]);
                af[4] = (short)f2bf(a1[0]); af[5] = (short)f2bf(a1[1]);
                af[6] = (short)f2bf(a1[2]); af[7] = (short)f2bf(a1[3]);
                short8 bfr = bp[kk * 4];
                sacc = __builtin_amdgcn_mfma_f32_16x16x32_bf16(af, bfr, sacc, 0, 0, 0);
            }
            *(f32x4*)&sp[(wave * 64 + lane) * 4] = sacc;
        }
        __syncthreads();
        // p = exp(score)  (C/D layout: col=lane&15, row=quad*4+reg)
        if (tid < 256) {
            int m = tid >> 4, hh = tid & 15;
            int ln = (m >> 2) * 16 + hh, rg = m & 3;
            float s = c_ws[hh];
            #pragma unroll
            for (int w = 0; w < 8; w++) s += sp[(w * 64 + ln) * 4 + rg];
            float p = __expf(s);
            p_lds[m * 16 + hh] = p;
            atomicAdd(&esum[hh], p);
        }
        __syncthreads();
        // accumulate u partial: thread owns 2 cols x 16 heads
        #pragma unroll 4
        for (int m = 0; m < 16; m++) {
            float2 xv = *(const float2*)&x_lds[m * 1028 + tid * 2];
            const f32x4* pp = (const f32x4*)&p_lds[m * 16];
            #pragma unroll
            for (int g = 0; g < 4; g++) {
                f32x4 pv = pp[g];
                acc[(g * 4 + 0) * 2 + 0] += pv[0] * xv.x;
                acc[(g * 4 + 0) * 2 + 1] += pv[0] * xv.y;
                acc[(g * 4 + 1) * 2 + 0] += pv[1] * xv.x;
                acc[(g * 4 + 1) * 2 + 1] += pv[1] * xv.y;
                acc[(g * 4 + 2) * 2 + 0] += pv[2] * xv.x;
                acc[(g * 4 + 2) * 2 + 1] += pv[2] * xv.y;
                acc[(g * 4 + 3) * 2 + 0] += pv[3] * xv.x;
                acc[(g * 4 + 3) * 2 + 1] += pv[3] * xv.y;
            }
        }
    }
    __syncthreads();
    // store partials as packed bf16 (coalesced dwords, no atomics)
    #pragma unroll
    for (int h = 0; h < 16; h++) {
        unsigned int pk = (unsigned int)f2bf(acc[h * 2])
                        | ((unsigned int)f2bf(acc[h * 2 + 1]) << 16);
        partial_bf[(beta * 16 + h) * 512 + tid] = pk;
    }
    if (tid < 16) atomicAdd(&S_shard[(beta & 15) * 16 + tid], esum[tid]);
}

// k3: u[o] = sum over 256 chunks of bf16 partials. 256 blocks x 512 thr.
__global__ __launch_bounds__(512) void k3_reduce(
    const unsigned short* __restrict__ partial_bf, float* __restrict__ u_ws)
{
    __shared__ float red[8 * 64];
    int wave = threadIdx.x >> 6, lane = threadIdx.x & 63;
    int o = blockIdx.x * 64 + lane;          // 0..16383
    float s = 0.f;
    for (int bb = wave; bb < 256; bb += 8) s += bf2f(partial_bf[bb * (H * E) + o]);
    red[wave * 64 + lane] = s;
    __syncthreads();
    if (wave == 0) {
        float tot = 0.f;
        #pragma unroll
        for (int w = 0; w < 8; w++) tot += red[w * 64 + lane];
        u_ws[o] = tot;
    }
}

// k4: oh[i] = (Wv[i,:].u_h)/S_h + bv[i]. One wave per output.
__global__ __launch_bounds__(256) void k4_oh(
    const float* __restrict__ W, const float* __restrict__ bias,
    const float* __restrict__ u_ws, const float* __restrict__ S_shard,
    float* __restrict__ oh_ws)
{
    int wave = threadIdx.x >> 6, lane = threadIdx.x & 63;
    int i = blockIdx.x * 4 + wave;
    int h = i >> 6;
    float Sh = 0.f;
    #pragma unroll
    for (int sh = 0; sh < NSHARD; sh++) Sh += S_shard[sh * 16 + h];
    const f32x4* wp = (const f32x4*)(W + (2 * E + i) * E) + lane * 4;
    const f32x4* up = (const f32x4*)(u_ws + h * E) + lane * 4;
    float s = 0.f;
    #pragma unroll
    for (int j = 0; j < 4; j++) {
        f32x4 w4 = wp[j], u4 = up[j];
        s += w4[0]*u4[0] + w4[1]*u4[1] + w4[2]*u4[2] + w4[3]*u4[3];
    }
    s = wave_reduce_sum(s);
    if (lane == 0) oh_ws[i] = s / Sh + bias[2 * E + i];
}

// k5: out[j] = Wout[j,:].oh + bout[j]. One wave per output.
__global__ __launch_bounds__(256) void k5_out(
    const float* __restrict__ Wout, const float* __restrict__ bout,
    const float* __restrict__ oh_ws, float* __restrict__ out)
{
    int wave = threadIdx.x >> 6, lane = threadIdx.x & 63;
    int j = blockIdx.x * 4 + wave;
    const f32x4* wp = (const f32x4*)(Wout + j * E) + lane * 4;
    const f32x4* op = (const f32x4*)(oh_ws) + lane * 4;
    float s = 0.f;
    #pragma unroll
    for (int jj = 0; jj < 4; jj++) {
        f32x4 w4 = wp[jj], o4 = op[jj];
        s += w4[0]*o4[0] + w4[1]*o4[1] + w4[2]*o4[2] + w4[3]*o4[3];
    }
    s = wave_reduce_sum(s);
    if (lane == 0) out[j] = s + bout[j];
}

extern "C" void kernel_launch(void* const* d_in, const int* in_sizes, int n_in,
                              void* d_out, int out_size, void* d_ws, size_t ws_size,
                              hipStream_t stream) {
    const float* x  = (const float*)d_in[0];
    const float* W  = (const float*)d_in[1];
    const float* b  = (const float*)d_in[2];
    const float* Wo = (const float*)d_in[3];
    const float* bo = (const float*)d_in[4];
    float* out = (float*)d_out;
    char* ws = (char*)d_ws;

    float* c_ws    = (float*)(ws);                  // 64 B
    float* S_shard = (float*)(ws + 1024);           // 1 KB (16 shards x 16 h)
    float* oh_ws   = (float*)(ws + 4096);           // 4 KB
    unsigned short* r_bf = (unsigned short*)(ws + 8192);  // 32 KB
    float* u_ws    = (float*)(ws + 65536);          // 64 KB
    unsigned int* partial_bf = (unsigned int*)(ws + 131072);  // 8 MB

    hipLaunchKernelGGL(kA_qrc,  dim3(256), dim3(256), 0, stream,
                       x, W, b, r_bf, c_ws, S_shard);
    hipLaunchKernelGGL(k2_fused, dim3(256), dim3(512), 0, stream,
                       x, r_bf, c_ws, partial_bf, S_shard);
    hipLaunchKernelGGL(k3_reduce, dim3(256), dim3(512), 0, stream,
                       (const unsigned short*)partial_bf, u_ws);
    hipLaunchKernelGGL(k4_oh,   dim3(256), dim3(256), 0, stream,
                       W, b, u_ws, S_shard, oh_ws);
    hipLaunchKernelGGL(k5_out,  dim3(256), dim3(256), 0, stream,
                       Wo, bo, oh_ws, out);
}

// Round 7
// 108.824 us; speedup vs baseline: 1.3108x; 1.1490x over previous
//
#include <hip/hip_runtime.h>

#define LSEQ 8192
#define E 1024
#define H 16
#define NSHARD 16

typedef __attribute__((ext_vector_type(8))) short short8;
typedef __attribute__((ext_vector_type(4))) float f32x4;

__device__ inline float bf2f(unsigned int u16) {
    union { unsigned int i; float f; } v;
    v.i = (u16 & 0xffffu) << 16;
    return v.f;
}

__device__ inline unsigned short f2bf(float f) {
    union { float f; unsigned int i; } v; v.f = f;
    unsigned int x = v.i;
    return (unsigned short)((x + 0x7fffu + ((x >> 16) & 1u)) >> 16);
}

__device__ inline float wave_reduce_sum(float v) {
    #pragma unroll
    for (int off = 32; off > 0; off >>= 1) v += __shfl_xor(v, off, 64);
    return v;
}

// k0: q[i] = Wq[i,:].x0 + bq[i]. One wave per output; block 0 zeroes S_shard.
__global__ __launch_bounds__(256) void k0_q(
    const float* __restrict__ x, const float* __restrict__ W,
    const float* __restrict__ bias, float* __restrict__ q_ws,
    float* __restrict__ S_shard)
{
    if (blockIdx.x == 0) S_shard[threadIdx.x] = 0.f;   // 256 = NSHARD*16
    int wave = threadIdx.x >> 6, lane = threadIdx.x & 63;
    int i = blockIdx.x * 4 + wave;
    const f32x4* wp = (const f32x4*)(W + i * E) + lane * 4;
    const f32x4* xp = (const f32x4*)(x) + lane * 4;
    float s = 0.f;
    #pragma unroll
    for (int j = 0; j < 4; j++) {
        f32x4 w4 = wp[j], x4 = xp[j];
        s += w4[0]*x4[0] + w4[1]*x4[1] + w4[2]*x4[2] + w4[3]*x4[3];
    }
    s = wave_reduce_sum(s);
    if (lane == 0) q_ws[i] = s + bias[i];
}

// k1: r_bf[h][e] = bf16(0.125 * Wk_h^T q_h); c[h] = 0.125 * q_h . bk_h
__global__ __launch_bounds__(256) void k1_rc(
    const float* __restrict__ W, const float* __restrict__ bias,
    const float* __restrict__ q_ws, unsigned short* __restrict__ r_bf,
    float* __restrict__ c_ws)
{
    __shared__ float red[4][64];
    int hb = blockIdx.x >> 4, ec = blockIdx.x & 15;
    int lane = threadIdx.x & 63, wq = threadIdx.x >> 6;
    int e = ec * 64 + lane;
    const float* qh = q_ws + hb * 64;
    float acc = 0.f;
    #pragma unroll
    for (int i = 0; i < 16; i++) {
        int d = wq * 16 + i;
        acc += qh[d] * W[(E + hb * 64 + d) * E + e];
    }
    red[wq][lane] = acc;
    __syncthreads();
    if (wq == 0) {
        float s = red[0][lane] + red[1][lane] + red[2][lane] + red[3][lane];
        r_bf[hb * E + e] = f2bf(s * 0.125f);
    }
    if (ec == 0 && wq == 1) {
        float v = qh[lane] * bias[E + hb * 64 + lane];
        v = wave_reduce_sum(v);
        if (lane == 0) c_ws[hb] = v * 0.125f;
    }
}

// k2: single pass over x. Block beta owns rows [beta*32, beta*32+32):
//   scores via MFMA -> p = exp(score) (no max; scores ~ N(0,1))
//   -> register u-partials -> plain store as packed bf16 (no atomics)
//   -> S_shard[beta&15] += esum (low-contention atomics)
__global__ __launch_bounds__(512, 1) void k2_fused(
    const float* __restrict__ x,
    const unsigned short* __restrict__ r_bf,
    const float* __restrict__ c_ws,
    unsigned int* __restrict__ partial_bf, float* __restrict__ S_shard)
{
    __shared__ float x_lds[16 * 1028];   // 16 rows, stride 1028 (pad 4)
    __shared__ float sp[8 * 64 * 4];     // per-wave MFMA partials
    __shared__ float p_lds[16 * 16];     // [row][head]
    __shared__ float esum[16];

    const int tid  = threadIdx.x;
    const int wave = tid >> 6, lane = tid & 63;
    const int beta = blockIdx.x;

    if (tid < 16) esum[tid] = 0.f;
    float acc[32];   // 16 heads x 2 cols (cols tid*2, tid*2+1)
    #pragma unroll
    for (int i = 0; i < 32; i++) acc[i] = 0.f;
    int lbase = beta * 32;

    for (int t = 0; t < 2; t++) {
        int R0 = lbase + t * 16;
        __syncthreads();
        // stage 16 fp32 rows into LDS (coalesced)
        {
            int row = tid >> 5, ch = tid & 31;
            const f32x4* src = (const f32x4*)(x + (R0 + row) * E);
            float* dst = x_lds + row * 1028;
            #pragma unroll
            for (int j = 0; j < 8; j++) {
                int c4 = ch + 32 * j;
                *(f32x4*)(dst + c4 * 4) = src[c4];
            }
        }
        __syncthreads();
        // MFMA: wave w covers K window [w*128, w*128+128)
        {
            int rw = lane & 15, quad = lane >> 4;
            f32x4 sacc = {0.f, 0.f, 0.f, 0.f};
            const float* arow = x_lds + rw * 1028 + wave * 128 + quad * 8;
            const short8* bp = (const short8*)(r_bf + rw * E + wave * 128 + quad * 8);
            #pragma unroll
            for (int kk = 0; kk < 4; kk++) {
                f32x4 a0 = *(const f32x4*)(arow + kk * 32);
                f32x4 a1 = *(const f32x4*)(arow + kk * 32 + 4);
                short8 af;
                af[0] = (short)f2bf(a0[0]); af[1] = (short)f2bf(a0[1]);
                af[2] = (short)f2bf(a0[2]); af[3] = (short)f2bf(a0[3]);
                af[4] = (short)f2bf(a1[0]); af[5] = (short)f2bf(a1[1]);
                af[6] = (short)f2bf(a1[2]); af[7] = (short)f2bf(a1[3]);
                short8 bfr = bp[kk * 4];
                sacc = __builtin_amdgcn_mfma_f32_16x16x32_bf16(af, bfr, sacc, 0, 0, 0);
            }
            *(f32x4*)&sp[(wave * 64 + lane) * 4] = sacc;
        }
        __syncthreads();
        // p = exp(score)  (C/D layout: col=lane&15, row=quad*4+reg)
        if (tid < 256) {
            int m = tid >> 4, hh = tid & 15;
            int ln = (m >> 2) * 16 + hh, rg = m & 3;
            float s = c_ws[hh];
            #pragma unroll
            for (int w = 0; w < 8; w++) s += sp[(w * 64 + ln) * 4 + rg];
            float p = __expf(s);
            p_lds[m * 16 + hh] = p;
            atomicAdd(&esum[hh], p);
        }
        __syncthreads();
        // accumulate u partial: thread owns 2 cols x 16 heads
        #pragma unroll 4
        for (int m = 0; m < 16; m++) {
            float2 xv = *(const float2*)&x_lds[m * 1028 + tid * 2];
            const f32x4* pp = (const f32x4*)&p_lds[m * 16];
            #pragma unroll
            for (int g = 0; g < 4; g++) {
                f32x4 pv = pp[g];
                acc[(g * 4 + 0) * 2 + 0] += pv[0] * xv.x;
                acc[(g * 4 + 0) * 2 + 1] += pv[0] * xv.y;
                acc[(g * 4 + 1) * 2 + 0] += pv[1] * xv.x;
                acc[(g * 4 + 1) * 2 + 1] += pv[1] * xv.y;
                acc[(g * 4 + 2) * 2 + 0] += pv[2] * xv.x;
                acc[(g * 4 + 2) * 2 + 1] += pv[2] * xv.y;
                acc[(g * 4 + 3) * 2 + 0] += pv[3] * xv.x;
                acc[(g * 4 + 3) * 2 + 1] += pv[3] * xv.y;
            }
        }
    }
    __syncthreads();
    // store partials as packed bf16 (coalesced dwords, no atomics)
    #pragma unroll
    for (int h = 0; h < 16; h++) {
        unsigned int pk = (unsigned int)f2bf(acc[h * 2])
                        | ((unsigned int)f2bf(acc[h * 2 + 1]) << 16);
        partial_bf[(beta * 16 + h) * 512 + tid] = pk;
    }
    if (tid < 16) atomicAdd(&S_shard[(beta & 15) * 16 + tid], esum[tid]);
}

// k3: u[2c..2c+1] = sum over 256 chunks of packed-bf16 partial col c.
// 128 blocks x 512 thr; each block owns 64 uint cols (128 fp32 outputs).
__global__ __launch_bounds__(512) void k3_reduce(
    const unsigned int* __restrict__ partial_bf, float2* __restrict__ u_ws2)
{
    __shared__ float red[8][64][2];
    int wave = threadIdx.x >> 6, lane = threadIdx.x & 63;
    int col = blockIdx.x * 64 + lane;        // 0..8191 uint columns
    float s0 = 0.f, s1 = 0.f;
    #pragma unroll 8
    for (int bb = wave; bb < 256; bb += 8) {
        unsigned int v = partial_bf[bb * 8192 + col];
        s0 += bf2f(v);
        s1 += bf2f(v >> 16);
    }
    red[wave][lane][0] = s0;
    red[wave][lane][1] = s1;
    __syncthreads();
    if (wave == 0) {
        float t0 = 0.f, t1 = 0.f;
        #pragma unroll
        for (int w = 0; w < 8; w++) { t0 += red[w][lane][0]; t1 += red[w][lane][1]; }
        float2 o; o.x = t0; o.y = t1;
        u_ws2[col] = o;
    }
}

// k4: oh[i] = (Wv[i,:].u_h)/S_h + bv[i]. One wave per output.
__global__ __launch_bounds__(256) void k4_oh(
    const float* __restrict__ W, const float* __restrict__ bias,
    const float* __restrict__ u_ws, const float* __restrict__ S_shard,
    float* __restrict__ oh_ws)
{
    int wave = threadIdx.x >> 6, lane = threadIdx.x & 63;
    int i = blockIdx.x * 4 + wave;
    int h = i >> 6;
    float Sh = 0.f;
    #pragma unroll
    for (int sh = 0; sh < NSHARD; sh++) Sh += S_shard[sh * 16 + h];
    const f32x4* wp = (const f32x4*)(W + (2 * E + i) * E) + lane * 4;
    const f32x4* up = (const f32x4*)(u_ws + h * E) + lane * 4;
    float s = 0.f;
    #pragma unroll
    for (int j = 0; j < 4; j++) {
        f32x4 w4 = wp[j], u4 = up[j];
        s += w4[0]*u4[0] + w4[1]*u4[1] + w4[2]*u4[2] + w4[3]*u4[3];
    }
    s = wave_reduce_sum(s);
    if (lane == 0) oh_ws[i] = s / Sh + bias[2 * E + i];
}

// k5: out[j] = Wout[j,:].oh + bout[j]. One wave per output.
__global__ __launch_bounds__(256) void k5_out(
    const float* __restrict__ Wout, const float* __restrict__ bout,
    const float* __restrict__ oh_ws, float* __restrict__ out)
{
    int wave = threadIdx.x >> 6, lane = threadIdx.x & 63;
    int j = blockIdx.x * 4 + wave;
    const f32x4* wp = (const f32x4*)(Wout + j * E) + lane * 4;
    const f32x4* op = (const f32x4*)(oh_ws) + lane * 4;
    float s = 0.f;
    #pragma unroll
    for (int jj = 0; jj < 4; jj++) {
        f32x4 w4 = wp[jj], o4 = op[jj];
        s += w4[0]*o4[0] + w4[1]*o4[1] + w4[2]*o4[2] + w4[3]*o4[3];
    }
    s = wave_reduce_sum(s);
    if (lane == 0) out[j] = s + bout[j];
}

extern "C" void kernel_launch(void* const* d_in, const int* in_sizes, int n_in,
                              void* d_out, int out_size, void* d_ws, size_t ws_size,
                              hipStream_t stream) {
    const float* x  = (const float*)d_in[0];
    const float* W  = (const float*)d_in[1];
    const float* b  = (const float*)d_in[2];
    const float* Wo = (const float*)d_in[3];
    const float* bo = (const float*)d_in[4];
    float* out = (float*)d_out;
    char* ws = (char*)d_ws;

    float* c_ws    = (float*)(ws);                  // 64 B
    float* S_shard = (float*)(ws + 1024);           // 1 KB (16 shards x 16 h)
    float* oh_ws   = (float*)(ws + 4096);           // 4 KB
    float* q_ws    = (float*)(ws + 12288);          // 4 KB
    unsigned short* r_bf = (unsigned short*)(ws + 16384); // 32 KB
    float* u_ws    = (float*)(ws + 65536);          // 64 KB
    unsigned int* partial_bf = (unsigned int*)(ws + 131072);  // 8 MB

    hipLaunchKernelGGL(k0_q,     dim3(256), dim3(256), 0, stream,
                       x, W, b, q_ws, S_shard);
    hipLaunchKernelGGL(k1_rc,    dim3(256), dim3(256), 0, stream,
                       W, b, q_ws, r_bf, c_ws);
    hipLaunchKernelGGL(k2_fused, dim3(256), dim3(512), 0, stream,
                       x, r_bf, c_ws, partial_bf, S_shard);
    hipLaunchKernelGGL(k3_reduce, dim3(128), dim3(512), 0, stream,
                       partial_bf, (float2*)u_ws);
    hipLaunchKernelGGL(k4_oh,    dim3(256), dim3(256), 0, stream,
                       W, b, u_ws, S_shard, oh_ws);
    hipLaunchKernelGGL(k5_out,   dim3(256), dim3(256), 0, stream,
                       Wo, bo, oh_ws, out);
}